// Round 3
// baseline (145.620 us; speedup 1.0000x reference)
//
#include <hip/hip_runtime.h>
#include <stdint.h>

typedef _Float16 f16;
typedef __attribute__((ext_vector_type(2))) _Float16 f16x2;
typedef __attribute__((ext_vector_type(4))) _Float16 f16x4;
typedef __attribute__((ext_vector_type(8))) _Float16 f16x8;
typedef __attribute__((ext_vector_type(4))) float f32x4;

#define H0 64
#define W0 128
#define NPIX 8192   // H0*W0
#define KD 256
#define NCAT 10880  // 8192 + 2048 + 512 + 128  (= 85 * 128, exact)
#define OFF1 8192
#define OFF2 10240
#define OFF3 10752

// ---------------------------------------------------------------------------
// 1) transpose + fp32->fp16: in [256][8192] (d-major) -> out [8192][256]
// ---------------------------------------------------------------------------
__global__ __launch_bounds__(256) void transpose_cvt(const float* __restrict__ in,
                                                     f16* __restrict__ out) {
  __shared__ f16 tile[64][65];
  int t = threadIdx.x;
  int m0 = blockIdx.x * 64;
  int d0 = blockIdx.y * 64;
  int a = t & 63;
  int b = t >> 6;
#pragma unroll
  for (int i = 0; i < 16; ++i) {
    int d = b + i * 4;
    tile[a][d] = (f16)in[(size_t)(d0 + d) * NPIX + m0 + a];
  }
  __syncthreads();
#pragma unroll
  for (int i = 0; i < 16; ++i) {
    int m = b + i * 4;
    out[(size_t)(m0 + m) * KD + d0 + a] = tile[m][a];
  }
}

// ---------------------------------------------------------------------------
// 2) pooled feature rows: Bc rows [8192,10880) = 2x2/4x4/8x8 pixel means of
//    Bc rows [0,8192). (avg-pool commutes with the correlation dot product.)
// ---------------------------------------------------------------------------
__global__ __launch_bounds__(256) void pool_feat(f16* __restrict__ Bc) {
  int idx = blockIdx.x * 256 + threadIdx.x;  // 336*256 = 86016 = 2688*32 exact
  int dc = idx & 31;                         // d-chunk of 8
  int r  = idx >> 5;                         // 0..2687 pooled row
  int lev, y, x;
  if (r < 2048)      { lev = 1; y = r >> 6;          x = r & 63; }
  else if (r < 2560) { lev = 2; y = (r - 2048) >> 5; x = (r - 2048) & 31; }
  else               { lev = 3; y = (r - 2560) >> 4; x = (r - 2560) & 15; }
  int sz = 1 << lev;
  float acc[8] = {0, 0, 0, 0, 0, 0, 0, 0};
  for (int h = 0; h < sz; ++h)
    for (int ww = 0; ww < sz; ++ww) {
      f16x8 v = *(const f16x8*)(Bc + (size_t)((y * sz + h) * W0 + x * sz + ww) * KD + dc * 8);
#pragma unroll
      for (int e = 0; e < 8; ++e) acc[e] += (float)v[e];
    }
  float s = 1.0f / (float)(sz * sz);
  f16x8 o;
#pragma unroll
  for (int e = 0; e < 8; ++e) o[e] = (f16)(acc[e] * s);
  *(f16x8*)(Bc + (size_t)(8192 + r) * KD + dc * 8) = o;
}

// ---------------------------------------------------------------------------
// 3) GEMM: C[m][n] = (1/16) * sum_k A[m][k]*B[n][k], M=8192, N=10880, K=256.
//    256x128 tile, 4 waves of 128x64, BK=32, double-buffered LDS with
//    2-deep counted-vmcnt prefetch; 2-rows-per-128B-line XOR-swizzled LDS
//    (conflict-free), linear gload_lds dest + inverse-swizzled source.
// ---------------------------------------------------------------------------
#define GLD16(gp, lp)                                                          \
  __builtin_amdgcn_global_load_lds(                                            \
      (const __attribute__((address_space(1))) void*)(gp),                     \
      (__attribute__((address_space(3))) void*)(lp), 16, 0, 0)

__global__ __launch_bounds__(256, 2) void corr_gemm(const f16* __restrict__ A,
                                                    const f16* __restrict__ B,
                                                    f16* __restrict__ C) {
  __shared__ f16 lds[24576];  // 48 KB: buf{0,1} x (A 8192 f16 | B 4096 f16)

  int bid = blockIdx.x;                     // 2720 = 32 bm x 85 bn
  int swz = (bid & 7) * 340 + (bid >> 3);   // bijective XCD swizzle (2720%8==0)
  int bm = (swz & 31) << 8;                 // bm fastest -> B-tile L2-resident
  int bn = (swz >> 5) << 7;

  int t = threadIdx.x;
  int lane = t & 63;
  int w = t >> 6;
  int wm = (w >> 1) * 128;
  int wn = (w & 1) * 64;
  int lr = lane & 15;
  int ko = lane >> 4;

  // read byte-offsets: row pairs packed per 128B line, slot ^= (line&7)
  int offA[8], offB[4];
#pragma unroll
  for (int i = 0; i < 8; ++i) {
    int row = wm + i * 16 + lr;
    int line = row >> 1;
    int phys = (((row & 1) << 2) | ko) ^ (line & 7);
    offA[i] = line * 128 + phys * 16;
  }
#pragma unroll
  for (int i = 0; i < 4; ++i) {
    int row = wn + i * 16 + lr;
    int line = row >> 1;
    int phys = (((row & 1) << 2) | ko) ^ (line & 7);
    offB[i] = line * 128 + phys * 16;
  }

  // staging sources: linear LDS chunk c -> inverse-swizzled global (row,slot)
  const f16* srcA[4];
  const f16* srcB[2];
#pragma unroll
  for (int i = 0; i < 4; ++i) {
    int c = i * 256 + t;
    int line = c >> 3;
    int lg = (c & 7) ^ (line & 7);
    srcA[i] = A + (size_t)(bm + line * 2 + (lg >> 2)) * KD + (lg & 3) * 8;
  }
#pragma unroll
  for (int i = 0; i < 2; ++i) {
    int c = i * 256 + t;
    int line = c >> 3;
    int lg = (c & 7) ^ (line & 7);
    srcB[i] = B + (size_t)(bn + line * 2 + (lg >> 2)) * KD + (lg & 3) * 8;
  }

  auto STAGE = [&](int cur, int kt) {
    f16* dA = lds + cur * 12288;
    f16* dB = dA + 8192;
#pragma unroll
    for (int i = 0; i < 4; ++i) GLD16(srcA[i] + kt * 32, dA + i * 2048 + t * 8);
#pragma unroll
    for (int i = 0; i < 2; ++i) GLD16(srcB[i] + kt * 32, dB + i * 2048 + t * 8);
  };

  f32x4 acc[8][4];
#pragma unroll
  for (int i = 0; i < 8; ++i)
#pragma unroll
    for (int j = 0; j < 4; ++j) acc[i][j] = (f32x4){0.f, 0.f, 0.f, 0.f};

  STAGE(0, 0);
  STAGE(1, 1);

#pragma unroll
  for (int k = 0; k < 8; ++k) {
    const int cur = k & 1;
    if (k < 7) asm volatile("s_waitcnt vmcnt(6)" ::: "memory");
    else       asm volatile("s_waitcnt vmcnt(0)" ::: "memory");
    __builtin_amdgcn_s_barrier();           // buffer cur ready for all waves

    const char* ab = (const char*)(lds + cur * 12288);
    const char* bb = (const char*)(lds + cur * 12288 + 8192);
    f16x8 af[8], bf[4];
#pragma unroll
    for (int i = 0; i < 8; ++i) af[i] = *(const f16x8*)(ab + offA[i]);
#pragma unroll
    for (int i = 0; i < 4; ++i) bf[i] = *(const f16x8*)(bb + offB[i]);
    asm volatile("s_waitcnt lgkmcnt(0)" ::: "memory");
    __builtin_amdgcn_s_barrier();           // all reads done -> safe to refill
    if (k < 6) STAGE(cur, k + 2);
    __builtin_amdgcn_sched_barrier(0);      // keep prefetch issue before MFMA

    __builtin_amdgcn_s_setprio(1);
#pragma unroll
    for (int mi = 0; mi < 8; ++mi)
#pragma unroll
      for (int ni = 0; ni < 4; ++ni)
        acc[mi][ni] = __builtin_amdgcn_mfma_f32_16x16x32_f16(af[mi], bf[ni],
                                                             acc[mi][ni], 0, 0, 0);
    __builtin_amdgcn_s_setprio(0);
  }

  // epilogue: D[row=ko*4+r2][col=lr], scale 1/sqrt(256)
#pragma unroll
  for (int mi = 0; mi < 8; ++mi)
#pragma unroll
    for (int ni = 0; ni < 4; ++ni)
#pragma unroll
      for (int r2 = 0; r2 < 4; ++r2) {
        int row = bm + wm + mi * 16 + ko * 4 + r2;
        int col = bn + wn + ni * 16 + lr;
        C[(size_t)row * NCAT + col] = (f16)(acc[mi][ni][r2] * 0.0625f);
      }
}

// ---------------------------------------------------------------------------
// 4) bilinear window sampling from concat pyramid C[m][10880].
//    grid (32, 9, 4): m coalesced, j = window row, lev = pyramid level.
// ---------------------------------------------------------------------------
__global__ __launch_bounds__(256) void corr_sample(const f16* __restrict__ C,
                                                   const float* __restrict__ coords,
                                                   float* __restrict__ out) {
  int m = blockIdx.x * 256 + threadIdx.x;
  int j = blockIdx.y;
  int lev = blockIdx.z;
  int off, Hl, Wl;
  if (lev == 0)      { off = 0;    Hl = 64; Wl = 128; }
  else if (lev == 1) { off = OFF1; Hl = 32; Wl = 64; }
  else if (lev == 2) { off = OFF2; Hl = 16; Wl = 32; }
  else               { off = OFF3; Hl = 8;  Wl = 16; }

  float cx = coords[m];
  float cy = coords[NPIX + m];
  float inv = 1.0f / (float)(1 << lev);
  float xb = cx * inv, yb = cy * inv;
  float fx = floorf(xb), fy = floorf(yb);
  int X0 = (int)fx - 4, Y0 = (int)fy - 4;
  float wx1 = xb - fx, wx0 = 1.0f - wx1;
  float wy1 = yb - fy, wy0 = 1.0f - wy1;

  const f16* base = C + (size_t)m * NCAT + off;
  float* op = out + ((size_t)lev * 81 + (size_t)j * 9) * NPIX + m;

  float cur[10], nxt[10];
  {
    int y = Y0 + j;
    bool yin = (y >= 0) && (y < Hl);
    const f16* rp = base + y * Wl;
#pragma unroll
    for (int i = 0; i < 10; ++i) {
      int x = X0 + i;
      cur[i] = (yin && x >= 0 && x < Wl) ? (float)rp[x] : 0.0f;
    }
  }
  {
    int y = Y0 + j + 1;
    bool yin = (y >= 0) && (y < Hl);
    const f16* rp = base + y * Wl;
#pragma unroll
    for (int i = 0; i < 10; ++i) {
      int x = X0 + i;
      nxt[i] = (yin && x >= 0 && x < Wl) ? (float)rp[x] : 0.0f;
    }
  }
#pragma unroll
  for (int i = 0; i < 9; ++i) {
    float v = wy0 * (wx0 * cur[i] + wx1 * cur[i + 1])
            + wy1 * (wx0 * nxt[i] + wx1 * nxt[i + 1]);
    op[(size_t)i * NPIX] = v;
  }
}

// ---------------------------------------------------------------------------
extern "C" void kernel_launch(void* const* d_in, const int* in_sizes, int n_in,
                              void* d_out, int out_size, void* d_ws, size_t ws_size,
                              hipStream_t stream) {
  const float* fmap1  = (const float*)d_in[0];   // [1,256,64,128]
  const float* fmap2  = (const float*)d_in[1];
  const float* coords = (const float*)d_in[2];   // [1,2,64,128]
  float* out = (float*)d_out;                    // [1,324,64,128] fp32

  char* ws = (char*)d_ws;
  size_t offA = 0;
  size_t offB = offA + (size_t)NPIX * KD * 2;    // A: 4 MB
  size_t offC = offB + (size_t)NCAT * KD * 2;    // B: 5.44 MB
  size_t need = offC + (size_t)NPIX * NCAT * 2;  // C: 178.3 MB => 188.0 MB
  if (ws_size < need) return;

  f16* A  = (f16*)(ws + offA);
  f16* Bc = (f16*)(ws + offB);
  f16* C  = (f16*)(ws + offC);

  transpose_cvt<<<dim3(128, 4), 256, 0, stream>>>(fmap1, A);
  transpose_cvt<<<dim3(128, 4), 256, 0, stream>>>(fmap2, Bc);
  pool_feat<<<336, 256, 0, stream>>>(Bc);
  corr_gemm<<<2720, 256, 0, stream>>>(A, Bc, C);
  corr_sample<<<dim3(32, 9, 4), 256, 0, stream>>>(C, coords, out);
}

// Round 4
// 141.451 us; speedup vs baseline: 1.0295x; 1.0295x over previous
//
#include <hip/hip_runtime.h>
#include <stdint.h>

typedef _Float16 f16;
typedef __attribute__((ext_vector_type(2))) _Float16 f16x2;
typedef __attribute__((ext_vector_type(4))) _Float16 f16x4;
typedef __attribute__((ext_vector_type(8))) _Float16 f16x8;
typedef __attribute__((ext_vector_type(4))) float f32x4;

#define H0 64
#define W0 128
#define NPIX 8192   // H0*W0
#define KD 256
#define NCAT 10880  // 8192 + 2048 + 512 + 128  (= 85 * 128, exact)
#define OFF1 8192
#define OFF2 10240
#define OFF3 10752

// ---------------------------------------------------------------------------
// 1) transpose + fp32->fp16 for both fmaps: in [256][8192] -> out [8192][256]
//    blockIdx.z selects the input.
// ---------------------------------------------------------------------------
__global__ __launch_bounds__(256) void transpose_cvt(const float* __restrict__ in0,
                                                     const float* __restrict__ in1,
                                                     f16* __restrict__ out0,
                                                     f16* __restrict__ out1) {
  const float* in = blockIdx.z ? in1 : in0;
  f16* out = blockIdx.z ? out1 : out0;
  __shared__ f16 tile[64][65];
  int t = threadIdx.x;
  int m0 = blockIdx.x * 64;
  int d0 = blockIdx.y * 64;
  int a = t & 63;
  int b = t >> 6;
#pragma unroll
  for (int i = 0; i < 16; ++i) {
    int d = b + i * 4;
    tile[a][d] = (f16)in[(size_t)(d0 + d) * NPIX + m0 + a];
  }
  __syncthreads();
#pragma unroll
  for (int i = 0; i < 16; ++i) {
    int m = b + i * 4;
    out[(size_t)(m0 + m) * KD + d0 + a] = tile[m][a];
  }
}

// ---------------------------------------------------------------------------
// 2) pooled feature rows: Bc rows [8192,10880) = 2x2/4x4/8x8 pixel means of
//    Bc rows [0,8192). (avg-pool commutes with the correlation dot product.)
// ---------------------------------------------------------------------------
__global__ __launch_bounds__(256) void pool_feat(f16* __restrict__ Bc) {
  int idx = blockIdx.x * 256 + threadIdx.x;  // 336*256 = 86016 = 2688*32 exact
  int dc = idx & 31;                         // d-chunk of 8
  int r  = idx >> 5;                         // 0..2687 pooled row
  int lev, y, x;
  if (r < 2048)      { lev = 1; y = r >> 6;          x = r & 63; }
  else if (r < 2560) { lev = 2; y = (r - 2048) >> 5; x = (r - 2048) & 31; }
  else               { lev = 3; y = (r - 2560) >> 4; x = (r - 2560) & 15; }
  int sz = 1 << lev;
  float acc[8] = {0, 0, 0, 0, 0, 0, 0, 0};
  for (int h = 0; h < sz; ++h)
    for (int ww = 0; ww < sz; ++ww) {
      f16x8 v = *(const f16x8*)(Bc + (size_t)((y * sz + h) * W0 + x * sz + ww) * KD + dc * 8);
#pragma unroll
      for (int e = 0; e < 8; ++e) acc[e] += (float)v[e];
    }
  float s = 1.0f / (float)(sz * sz);
  f16x8 o;
#pragma unroll
  for (int e = 0; e < 8; ++e) o[e] = (f16)(acc[e] * s);
  *(f16x8*)(Bc + (size_t)(8192 + r) * KD + dc * 8) = o;
}

// ---------------------------------------------------------------------------
// 3) GEMM: C[m][n] = (1/16) * sum_k A[m][k]*B[n][k], M=8192, N=10880, K=256.
//    256x128 tile, 4 waves of 128x64, BK=32, double-buffered LDS, 2-deep
//    counted-vmcnt prefetch, XOR-swizzled operand LDS (conflict-free), and
//    an LDS-transposed epilogue emitting full-line dwordx4 stores (no RMW).
// ---------------------------------------------------------------------------
#define GLD16(gp, lp)                                                          \
  __builtin_amdgcn_global_load_lds(                                            \
      (const __attribute__((address_space(1))) void*)(gp),                     \
      (__attribute__((address_space(3))) void*)(lp), 16, 0, 0)

__global__ __launch_bounds__(256, 2) void corr_gemm(const f16* __restrict__ A,
                                                    const f16* __restrict__ B,
                                                    f16* __restrict__ C) {
  __shared__ f16 lds[24576];  // 48 KB: buf{0,1} x (A 8192 f16 | B 4096 f16)

  int bid = blockIdx.x;                     // 2720 = 32 bm x 85 bn
  int swz = (bid & 7) * 340 + (bid >> 3);   // bijective XCD swizzle (2720%8==0)
  int bm = (swz & 31) << 8;                 // bm fastest -> A L2-resident per group
  int bn = (swz >> 5) << 7;

  int t = threadIdx.x;
  int lane = t & 63;
  int w = t >> 6;
  int wm = (w >> 1) * 128;
  int wn = (w & 1) * 64;
  int lr = lane & 15;
  int ko = lane >> 4;

  // operand read byte-offsets: 2 rows per 128B line, slot ^= (line&7)
  int offA[8], offB[4];
#pragma unroll
  for (int i = 0; i < 8; ++i) {
    int row = wm + i * 16 + lr;
    int line = row >> 1;
    int phys = (((row & 1) << 2) | ko) ^ (line & 7);
    offA[i] = line * 128 + phys * 16;
  }
#pragma unroll
  for (int i = 0; i < 4; ++i) {
    int row = wn + i * 16 + lr;
    int line = row >> 1;
    int phys = (((row & 1) << 2) | ko) ^ (line & 7);
    offB[i] = line * 128 + phys * 16;
  }

  // staging sources: linear LDS chunk c -> inverse-swizzled global (row,slot)
  const f16* srcA[4];
  const f16* srcB[2];
#pragma unroll
  for (int i = 0; i < 4; ++i) {
    int c = i * 256 + t;
    int line = c >> 3;
    int lg = (c & 7) ^ (line & 7);
    srcA[i] = A + (size_t)(bm + line * 2 + (lg >> 2)) * KD + (lg & 3) * 8;
  }
#pragma unroll
  for (int i = 0; i < 2; ++i) {
    int c = i * 256 + t;
    int line = c >> 3;
    int lg = (c & 7) ^ (line & 7);
    srcB[i] = B + (size_t)(bn + line * 2 + (lg >> 2)) * KD + (lg & 3) * 8;
  }

  auto STAGE = [&](int cur, int kt) {
    f16* dA = lds + cur * 12288;
    f16* dB = dA + 8192;
#pragma unroll
    for (int i = 0; i < 4; ++i) GLD16(srcA[i] + kt * 32, dA + i * 2048 + t * 8);
#pragma unroll
    for (int i = 0; i < 2; ++i) GLD16(srcB[i] + kt * 32, dB + i * 2048 + t * 8);
  };

  f32x4 acc[8][4];
#pragma unroll
  for (int i = 0; i < 8; ++i)
#pragma unroll
    for (int j = 0; j < 4; ++j) acc[i][j] = (f32x4){0.f, 0.f, 0.f, 0.f};

  STAGE(0, 0);
  STAGE(1, 1);

#pragma unroll
  for (int k = 0; k < 8; ++k) {
    const int cur = k & 1;
    if (k < 7) asm volatile("s_waitcnt vmcnt(6)" ::: "memory");
    else       asm volatile("s_waitcnt vmcnt(0)" ::: "memory");
    __builtin_amdgcn_s_barrier();           // buffer cur ready for all waves

    const char* ab = (const char*)(lds + cur * 12288);
    const char* bb = (const char*)(lds + cur * 12288 + 8192);
    f16x8 af[8], bf[4];
#pragma unroll
    for (int i = 0; i < 8; ++i) af[i] = *(const f16x8*)(ab + offA[i]);
#pragma unroll
    for (int i = 0; i < 4; ++i) bf[i] = *(const f16x8*)(bb + offB[i]);
    asm volatile("s_waitcnt lgkmcnt(0)" ::: "memory");
    __builtin_amdgcn_s_barrier();           // all reads done -> safe to refill
    if (k < 6) STAGE(cur, k + 2);
    __builtin_amdgcn_sched_barrier(0);      // keep prefetch issue before MFMA

    __builtin_amdgcn_s_setprio(1);
#pragma unroll
    for (int mi = 0; mi < 8; ++mi)
#pragma unroll
      for (int ni = 0; ni < 4; ++ni)
        acc[mi][ni] = __builtin_amdgcn_mfma_f32_16x16x32_f16(af[mi], bf[ni],
                                                             acc[mi][ni], 0, 0, 0);
    __builtin_amdgcn_s_setprio(0);
  }

  // epilogue: per-wave LDS transpose (16x72 f16 region in buf0 -- safe: last
  // K-step reads buf1 and the reads-done barrier has passed), then full-line
  // f16x8 stores so TCC never read-modify-writes C lines.
  f16* eb = lds + w * 1152;
  int erow = lane >> 3;   // 0..7
  int ecol = lane & 7;    // 8-f16 chunk
#pragma unroll
  for (int mi = 0; mi < 8; ++mi) {
#pragma unroll
    for (int ni = 0; ni < 4; ++ni)
#pragma unroll
      for (int r2 = 0; r2 < 4; ++r2)
        eb[(ko * 4 + r2) * 72 + ni * 16 + lr] = (f16)(acc[mi][ni][r2] * 0.0625f);
#pragma unroll
    for (int h = 0; h < 2; ++h) {
      int row = h * 8 + erow;
      f16x8 v = *(const f16x8*)(eb + row * 72 + ecol * 8);
      int grow = bm + wm + mi * 16 + row;
      int gcol = bn + wn + ecol * 8;
      *(f16x8*)(C + (size_t)grow * NCAT + gcol) = v;
    }
  }
}

// ---------------------------------------------------------------------------
// 4) bilinear window sampling from concat pyramid C[m][10880].
//    bid layout packs the 9 j-blocks of one m-chunk onto one XCD (stride-8).
// ---------------------------------------------------------------------------
__global__ __launch_bounds__(256) void corr_sample(const f16* __restrict__ C,
                                                   const float* __restrict__ coords,
                                                   float* __restrict__ out) {
  int bx = blockIdx.x;            // 288 = 8 xcd * 36
  int xcd = bx & 7;
  int idx = bx >> 3;              // 0..35
  int j = idx % 9;                // window row
  int mc = xcd + 8 * (idx / 9);   // m-chunk 0..31
  int m = mc * 256 + threadIdx.x;
  int lev = blockIdx.z;
  int off, Hl, Wl;
  if (lev == 0)      { off = 0;    Hl = 64; Wl = 128; }
  else if (lev == 1) { off = OFF1; Hl = 32; Wl = 64; }
  else if (lev == 2) { off = OFF2; Hl = 16; Wl = 32; }
  else               { off = OFF3; Hl = 8;  Wl = 16; }

  float cx = coords[m];
  float cy = coords[NPIX + m];
  float inv = 1.0f / (float)(1 << lev);
  float xb = cx * inv, yb = cy * inv;
  float fx = floorf(xb), fy = floorf(yb);
  int X0 = (int)fx - 4, Y0 = (int)fy - 4;
  float wx1 = xb - fx, wx0 = 1.0f - wx1;
  float wy1 = yb - fy, wy0 = 1.0f - wy1;

  const f16* base = C + (size_t)m * NCAT + off;
  float* op = out + ((size_t)lev * 81 + (size_t)j * 9) * NPIX + m;

  float cur[10], nxt[10];
  {
    int y = Y0 + j;
    bool yin = (y >= 0) && (y < Hl);
    const f16* rp = base + y * Wl;
#pragma unroll
    for (int i = 0; i < 10; ++i) {
      int x = X0 + i;
      cur[i] = (yin && x >= 0 && x < Wl) ? (float)rp[x] : 0.0f;
    }
  }
  {
    int y = Y0 + j + 1;
    bool yin = (y >= 0) && (y < Hl);
    const f16* rp = base + y * Wl;
#pragma unroll
    for (int i = 0; i < 10; ++i) {
      int x = X0 + i;
      nxt[i] = (yin && x >= 0 && x < Wl) ? (float)rp[x] : 0.0f;
    }
  }
#pragma unroll
  for (int i = 0; i < 9; ++i) {
    float v = wy0 * (wx0 * cur[i] + wx1 * cur[i + 1])
            + wy1 * (wx0 * nxt[i] + wx1 * nxt[i + 1]);
    op[(size_t)i * NPIX] = v;
  }
}

// ---------------------------------------------------------------------------
extern "C" void kernel_launch(void* const* d_in, const int* in_sizes, int n_in,
                              void* d_out, int out_size, void* d_ws, size_t ws_size,
                              hipStream_t stream) {
  const float* fmap1  = (const float*)d_in[0];   // [1,256,64,128]
  const float* fmap2  = (const float*)d_in[1];
  const float* coords = (const float*)d_in[2];   // [1,2,64,128]
  float* out = (float*)d_out;                    // [1,324,64,128] fp32

  char* ws = (char*)d_ws;
  size_t offA = 0;
  size_t offB = offA + (size_t)NPIX * KD * 2;    // A: 4 MB
  size_t offC = offB + (size_t)NCAT * KD * 2;    // B: 5.44 MB
  size_t need = offC + (size_t)NPIX * NCAT * 2;  // C: 178.3 MB => 188.0 MB
  if (ws_size < need) return;

  f16* A  = (f16*)(ws + offA);
  f16* Bc = (f16*)(ws + offB);
  f16* C  = (f16*)(ws + offC);

  transpose_cvt<<<dim3(128, 4, 2), 256, 0, stream>>>(fmap1, fmap2, A, Bc);
  pool_feat<<<336, 256, 0, stream>>>(Bc);
  corr_gemm<<<2720, 256, 0, stream>>>(A, Bc, C);
  corr_sample<<<dim3(288, 1, 4), 256, 0, stream>>>(C, coords, out);
}

// Round 5
// 115.345 us; speedup vs baseline: 1.2625x; 1.2263x over previous
//
#include <hip/hip_runtime.h>
#include <stdint.h>

typedef _Float16 f16;
typedef __attribute__((ext_vector_type(2))) _Float16 f16x2;
typedef __attribute__((ext_vector_type(4))) _Float16 f16x4;
typedef __attribute__((ext_vector_type(8))) _Float16 f16x8;
typedef __attribute__((ext_vector_type(4))) float f32x4;

#define H0 64
#define W0 128
#define NPIX 8192   // H0*W0
#define KD 256
#define NCAT 10880  // 8192 + 2048 + 512 + 128  (= 85 * 128, exact)
#define OFF1 8192
#define OFF2 10240
#define OFF3 10752

// ---------------------------------------------------------------------------
// 1) transpose + fp32->fp16 for both fmaps: in [256][8192] -> out [8192][256]
// ---------------------------------------------------------------------------
__global__ __launch_bounds__(256) void transpose_cvt(const float* __restrict__ in0,
                                                     const float* __restrict__ in1,
                                                     f16* __restrict__ out0,
                                                     f16* __restrict__ out1) {
  const float* in = blockIdx.z ? in1 : in0;
  f16* out = blockIdx.z ? out1 : out0;
  __shared__ f16 tile[64][65];
  int t = threadIdx.x;
  int m0 = blockIdx.x * 64;
  int d0 = blockIdx.y * 64;
  int a = t & 63;
  int b = t >> 6;
#pragma unroll
  for (int i = 0; i < 16; ++i) {
    int d = b + i * 4;
    tile[a][d] = (f16)in[(size_t)(d0 + d) * NPIX + m0 + a];
  }
  __syncthreads();
#pragma unroll
  for (int i = 0; i < 16; ++i) {
    int m = b + i * 4;
    out[(size_t)(m0 + m) * KD + d0 + a] = tile[m][a];
  }
}

// ---------------------------------------------------------------------------
// 2) pooled feature rows: Bc rows [8192,10880) = 2x2/4x4/8x8 pixel means.
// ---------------------------------------------------------------------------
__global__ __launch_bounds__(256) void pool_feat(f16* __restrict__ Bc) {
  int idx = blockIdx.x * 256 + threadIdx.x;  // 86016 = 2688*32
  int dc = idx & 31;
  int r  = idx >> 5;
  int lev, y, x;
  if (r < 2048)      { lev = 1; y = r >> 6;          x = r & 63; }
  else if (r < 2560) { lev = 2; y = (r - 2048) >> 5; x = (r - 2048) & 31; }
  else               { lev = 3; y = (r - 2560) >> 4; x = (r - 2560) & 15; }
  int sz = 1 << lev;
  float acc[8] = {0, 0, 0, 0, 0, 0, 0, 0};
  for (int h = 0; h < sz; ++h)
    for (int ww = 0; ww < sz; ++ww) {
      f16x8 v = *(const f16x8*)(Bc + (size_t)((y * sz + h) * W0 + x * sz + ww) * KD + dc * 8);
#pragma unroll
      for (int e = 0; e < 8; ++e) acc[e] += (float)v[e];
    }
  float s = 1.0f / (float)(sz * sz);
  f16x8 o;
#pragma unroll
  for (int e = 0; e < 8; ++e) o[e] = (f16)(acc[e] * s);
  *(f16x8*)(Bc + (size_t)(8192 + r) * KD + dc * 8) = o;
}

// ---------------------------------------------------------------------------
// 3) GEMM: C[m][n] = (1/16)*sum_k A[m][k]*B[n][k], M=8192, N=10880, K=256.
//    256x128 tile, 4 waves of 64x128, BK=32, 3-ring LDS (72 KB dynamic),
//    counted vmcnt(12) prefetch, XCD-local bm (A L2-resident), XOR-swizzled
//    operand LDS, conflict-free LDS-transpose epilogue with 256B nt stores.
// ---------------------------------------------------------------------------
#define GLD16(gp, lp)                                                          \
  __builtin_amdgcn_global_load_lds(                                            \
      (const __attribute__((address_space(1))) void*)(gp),                     \
      (__attribute__((address_space(3))) void*)(lp), 16, 0, 0)

__global__ __launch_bounds__(256, 2) void corr_gemm(const f16* __restrict__ A,
                                                    const f16* __restrict__ B,
                                                    f16* __restrict__ C) {
  extern __shared__ f16 lds[];   // 3 x 12288 f16 = 72 KB ring

  int bid = blockIdx.x;          // 2720 = 8 xcd x (4 bm x 85 bn)
  // XCD x owns bm tiles [x*4, x*4+4): bm fastest, bn slowest ->
  // per-XCD A working set = 512 KB (L2-resident), B streamed once.
  int bm = (((bid & 7) << 2) | ((bid >> 3) & 3)) << 8;
  int bn = (bid >> 5) << 7;

  int t = threadIdx.x;
  int lane = t & 63;
  int w = t >> 6;                 // wave 0..3, owns rows [w*64, w*64+64)
  int lr = lane & 15;
  int ko = lane >> 4;

  // operand read byte-offsets: 2 rows per 128B line, slot ^= (line&7)
  int offA[4], offB[8];
#pragma unroll
  for (int i = 0; i < 4; ++i) {
    int row = w * 64 + i * 16 + lr;
    int line = row >> 1;
    int phys = (((row & 1) << 2) | ko) ^ (line & 7);
    offA[i] = line * 128 + phys * 16;
  }
#pragma unroll
  for (int i = 0; i < 8; ++i) {
    int row = i * 16 + lr;
    int line = row >> 1;
    int phys = (((row & 1) << 2) | ko) ^ (line & 7);
    offB[i] = line * 128 + phys * 16;
  }

  // staging sources: linear LDS chunk c -> inverse-swizzled global (row,slot)
  const f16* srcA[4];
  const f16* srcB[2];
#pragma unroll
  for (int i = 0; i < 4; ++i) {
    int c = i * 256 + t;
    int line = c >> 3;
    int lg = (c & 7) ^ (line & 7);
    srcA[i] = A + (size_t)(bm + line * 2 + (lg >> 2)) * KD + (lg & 3) * 8;
  }
#pragma unroll
  for (int i = 0; i < 2; ++i) {
    int c = i * 256 + t;
    int line = c >> 3;
    int lg = (c & 7) ^ (line & 7);
    srcB[i] = B + (size_t)(bn + line * 2 + (lg >> 2)) * KD + (lg & 3) * 8;
  }

  auto STAGE = [&](int buf, int kt) {
    f16* dA = lds + buf * 12288;
    f16* dB = dA + 8192;
#pragma unroll
    for (int i = 0; i < 4; ++i) GLD16(srcA[i] + kt * 32, dA + i * 2048 + t * 8);
#pragma unroll
    for (int i = 0; i < 2; ++i) GLD16(srcB[i] + kt * 32, dB + i * 2048 + t * 8);
  };

  f32x4 acc[4][8];
#pragma unroll
  for (int i = 0; i < 4; ++i)
#pragma unroll
    for (int j = 0; j < 8; ++j) acc[i][j] = (f32x4){0.f, 0.f, 0.f, 0.f};

  STAGE(0, 0);
  STAGE(1, 1);
  STAGE(2, 2);

#pragma unroll
  for (int k = 0; k < 8; ++k) {
    const int buf = k % 3;
    if (k <= 5)      asm volatile("s_waitcnt vmcnt(12)" ::: "memory");
    else if (k == 6) asm volatile("s_waitcnt vmcnt(6)" ::: "memory");
    else             asm volatile("s_waitcnt vmcnt(0)" ::: "memory");
    __builtin_amdgcn_s_barrier();           // buffer k ready for all waves

    const char* ab = (const char*)(lds + buf * 12288);
    const char* bb = (const char*)(lds + buf * 12288 + 8192);
    f16x8 af[4], bf[8];
#pragma unroll
    for (int i = 0; i < 4; ++i) af[i] = *(const f16x8*)(ab + offA[i]);
#pragma unroll
    for (int i = 0; i < 8; ++i) bf[i] = *(const f16x8*)(bb + offB[i]);
    asm volatile("s_waitcnt lgkmcnt(0)" ::: "memory");
    __builtin_amdgcn_s_barrier();           // all reads done -> safe to refill
    if (k < 5) STAGE(buf, k + 3);
    __builtin_amdgcn_sched_barrier(0);      // keep prefetch issue before MFMA

    __builtin_amdgcn_s_setprio(1);
#pragma unroll
    for (int mi = 0; mi < 4; ++mi)
#pragma unroll
      for (int ni = 0; ni < 8; ++ni)
        acc[mi][ni] = __builtin_amdgcn_mfma_f32_16x16x32_f16(af[mi], bf[ni],
                                                             acc[mi][ni], 0, 0, 0);
    __builtin_amdgcn_s_setprio(0);
  }

  // epilogue: per-wave 16x132 LDS transpose (bank-verified free), then
  // 256B-per-instruction nontemporal stores (16 lanes cover a full row seg).
  f16* eb = lds + w * 2176;
  int erow = lane >> 4;   // 0..3
  int ecol = lane & 15;   // 8-f16 chunk 0..15
#pragma unroll
  for (int mi = 0; mi < 4; ++mi) {
#pragma unroll
    for (int ni = 0; ni < 8; ++ni)
#pragma unroll
      for (int r2 = 0; r2 < 4; ++r2)
        eb[(ko * 4 + r2) * 132 + ni * 16 + lr] = (f16)(acc[mi][ni][r2] * 0.0625f);
#pragma unroll
    for (int h = 0; h < 4; ++h) {
      int row = h * 4 + erow;
      f16x8 v = *(const f16x8*)(eb + row * 132 + ecol * 8);
      int grow = bm + w * 64 + mi * 16 + row;
      int gcol = bn + ecol * 8;
      __builtin_nontemporal_store(v, (f16x8*)(C + (size_t)grow * NCAT + gcol));
    }
  }
}

// ---------------------------------------------------------------------------
// 4) bilinear window sampling from concat pyramid C[m][10880].
//    Vectorized: 4 aligned f16x4 loads per window row + static extraction.
// ---------------------------------------------------------------------------
__global__ __launch_bounds__(256) void corr_sample(const f16* __restrict__ C,
                                                   const float* __restrict__ coords,
                                                   float* __restrict__ out) {
  int bx = blockIdx.x;            // 288 = 8 xcd * 36
  int xcd = bx & 7;
  int idx = bx >> 3;              // 0..35
  int j = idx % 9;                // window row
  int mc = xcd + 8 * (idx / 9);   // m-chunk 0..31
  int m = mc * 256 + threadIdx.x;
  int lev = blockIdx.z;
  int off, Hl, Wl;
  if (lev == 0)      { off = 0;    Hl = 64; Wl = 128; }
  else if (lev == 1) { off = OFF1; Hl = 32; Wl = 64; }
  else if (lev == 2) { off = OFF2; Hl = 16; Wl = 32; }
  else               { off = OFF3; Hl = 8;  Wl = 16; }

  float cx = coords[m];
  float cy = coords[NPIX + m];
  float inv = 1.0f / (float)(1 << lev);
  float xb = cx * inv, yb = cy * inv;
  float fx = floorf(xb), fy = floorf(yb);
  int X0 = (int)fx - 4, Y0 = (int)fy - 4;
  float wx1 = xb - fx, wx0 = 1.0f - wx1;
  float wy1 = yb - fy, wy0 = 1.0f - wy1;

  int a0 = X0 & ~3;       // 8B-aligned start
  int s  = X0 - a0;       // 0..3

  const f16* base = C + (size_t)m * NCAT + off;
  float* op = out + ((size_t)lev * 81 + (size_t)j * 9) * NPIX + m;

  // load one window row as 4 aligned f16x4 (16 values cover s+10 <= 13),
  // x-masked into e[16], then static extraction by s (4-way branch).
  auto loadrow = [&](float* row, int y) {
    f16x4 q[4];
    bool yin = (y >= 0) && (y < Hl);
    const f16* rp = base + y * Wl + a0;
#pragma unroll
    for (int c = 0; c < 4; ++c)
      q[c] = yin ? *(const f16x4*)(rp + c * 4) : (f16x4){0, 0, 0, 0};
    float e[16];
#pragma unroll
    for (int c = 0; c < 4; ++c)
#pragma unroll
      for (int u = 0; u < 4; ++u) {
        int xg = a0 + c * 4 + u;
        e[c * 4 + u] = (xg >= 0 && xg < Wl) ? (float)q[c][u] : 0.0f;
      }
    if (s == 0) {
#pragma unroll
      for (int i = 0; i < 10; ++i) row[i] = e[i];
    } else if (s == 1) {
#pragma unroll
      for (int i = 0; i < 10; ++i) row[i] = e[i + 1];
    } else if (s == 2) {
#pragma unroll
      for (int i = 0; i < 10; ++i) row[i] = e[i + 2];
    } else {
#pragma unroll
      for (int i = 0; i < 10; ++i) row[i] = e[i + 3];
    }
  };

  float cur[10], nxt[10];
  loadrow(cur, Y0 + j);
  loadrow(nxt, Y0 + j + 1);
#pragma unroll
  for (int i = 0; i < 9; ++i) {
    float v = wy0 * (wx0 * cur[i] + wx1 * cur[i + 1])
            + wy1 * (wx0 * nxt[i] + wx1 * nxt[i + 1]);
    op[(size_t)i * NPIX] = v;
  }
}

// ---------------------------------------------------------------------------
extern "C" void kernel_launch(void* const* d_in, const int* in_sizes, int n_in,
                              void* d_out, int out_size, void* d_ws, size_t ws_size,
                              hipStream_t stream) {
  const float* fmap1  = (const float*)d_in[0];   // [1,256,64,128]
  const float* fmap2  = (const float*)d_in[1];
  const float* coords = (const float*)d_in[2];   // [1,2,64,128]
  float* out = (float*)d_out;                    // [1,324,64,128] fp32

  char* ws = (char*)d_ws;
  size_t offA = 0;
  size_t offB = offA + (size_t)NPIX * KD * 2;    // A: 4 MB
  size_t offC = offB + (size_t)NCAT * KD * 2;    // B: 5.44 MB
  size_t need = offC + (size_t)NPIX * NCAT * 2;  // C: 178.3 MB => 188.0 MB
  if (ws_size < need) return;

  f16* A  = (f16*)(ws + offA);
  f16* Bc = (f16*)(ws + offB);
  f16* C  = (f16*)(ws + offC);

  const int LDS_BYTES = 3 * 12288 * 2;  // 72 KB
  hipFuncSetAttribute(reinterpret_cast<const void*>(corr_gemm),
                      hipFuncAttributeMaxDynamicSharedMemorySize, LDS_BYTES);

  transpose_cvt<<<dim3(128, 4, 2), 256, 0, stream>>>(fmap1, fmap2, A, Bc);
  pool_feat<<<336, 256, 0, stream>>>(Bc);
  corr_gemm<<<2720, 256, LDS_BYTES, stream>>>(A, Bc, C);
  corr_sample<<<dim3(288, 1, 4), 256, 0, stream>>>(C, coords, out);
}